// Round 5
// baseline (153.460 us; speedup 1.0000x reference)
//
#include <hip/hip_runtime.h>
#include <hip/hip_cooperative_groups.h>

namespace cg = cooperative_groups;

#define NPTS 16384
#define NSPLIT 64
#define CHUNK (NPTS / NSPLIT)        // 256 sources per chunk
#define TPT 4                        // targets per thread
#define TBLK (NPTS / (256 * TPT))    // 16 target blocks
#define NBLK (TBLK * NSPLIT)         // 1024 blocks = 4/CU, co-resident

// Fused cooperative kernel.
// Phase 1: block b=(tb,sc) computes partial min of d2=||s||^2-2t.s over its
//          source chunk for its 1024 targets -> ws[sc*NPTS + t].
// grid.sync()
// Phase 2: first 64 blocks reduce NSPLIT partials/target, add ||t||^2,
//          wave-reduce, atomicAdd into out (zeroed by block 0 pre-sync).
__global__ __launch_bounds__(256) void nn_fused(const float* __restrict__ src,
                                                const float* __restrict__ tar,
                                                float* __restrict__ ws,
                                                float* __restrict__ out) {
    const int tid = threadIdx.x;
    const int b   = blockIdx.x;
    const int tb  = b & (TBLK - 1);
    const int sc  = b >> 4;

    if (b == 0 && tid == 0) out[0] = 0.0f;   // replaces memset launch; visible after grid.sync

    __shared__ float4 sp[CHUNK];
    const int sbase = sc * CHUNK;
    {
        float x = src[(sbase + tid) * 3 + 0];
        float y = src[(sbase + tid) * 3 + 1];
        float z = src[(sbase + tid) * 3 + 2];
        sp[tid] = make_float4(-2.0f * x, -2.0f * y, -2.0f * z, x * x + y * y + z * z);
    }
    __syncthreads();

    const int t0 = tb * (256 * TPT) + tid;
    float tx[TPT], ty[TPT], tz[TPT], best[TPT];
#pragma unroll
    for (int k = 0; k < TPT; ++k) {
        const int t = t0 + k * 256;
        tx[k] = tar[t * 3 + 0];
        ty[k] = tar[t * 3 + 1];
        tz[k] = tar[t * 3 + 2];
        best[k] = 1e30f;
    }

    // R1-proposal inner loop (empirically best codegen): 3 FMA + 1 min per pair.
#pragma unroll 4
    for (int j = 0; j < CHUNK; ++j) {
        float4 s = sp[j];
#pragma unroll
        for (int k = 0; k < TPT; ++k) {
            float d = fmaf(tx[k], s.x, fmaf(ty[k], s.y, fmaf(tz[k], s.z, s.w)));
            best[k] = fminf(best[k], d);
        }
    }
#pragma unroll
    for (int k = 0; k < TPT; ++k)
        ws[sc * NPTS + t0 + k * 256] = best[k];

    cg::this_grid().sync();

    if (b < NPTS / 256) {                    // 64 blocks do the reduction
        const int t = b * 256 + tid;
        float m = 1e30f;
#pragma unroll 8
        for (int s2 = 0; s2 < NSPLIT; ++s2)
            m = fminf(m, ws[s2 * NPTS + t]);
        const float x = tar[t * 3 + 0], y = tar[t * 3 + 1], z = tar[t * 3 + 2];
        float v = 0.5f * (m + x * x + y * y + z * z);
        for (int off = 32; off > 0; off >>= 1) v += __shfl_down(v, off, 64);
        __shared__ float wsum[4];
        if ((tid & 63) == 0) wsum[tid >> 6] = v;
        __syncthreads();
        if (tid == 0) atomicAdd(out, wsum[0] + wsum[1] + wsum[2] + wsum[3]);
    }
}

// ---- Fallback path (non-cooperative), same math split in two kernels ----
__global__ __launch_bounds__(256) void nn_min(const float* __restrict__ src,
                                              const float* __restrict__ tar,
                                              float* __restrict__ ws) {
    const int tid = threadIdx.x;
    const int tb  = blockIdx.x;
    const int sc  = blockIdx.y;
    __shared__ float4 sp[CHUNK];
    const int sbase = sc * CHUNK;
    {
        float x = src[(sbase + tid) * 3 + 0];
        float y = src[(sbase + tid) * 3 + 1];
        float z = src[(sbase + tid) * 3 + 2];
        sp[tid] = make_float4(-2.0f * x, -2.0f * y, -2.0f * z, x * x + y * y + z * z);
    }
    __syncthreads();
    const int t0 = tb * (256 * TPT) + tid;
    float tx[TPT], ty[TPT], tz[TPT], best[TPT];
#pragma unroll
    for (int k = 0; k < TPT; ++k) {
        const int t = t0 + k * 256;
        tx[k] = tar[t * 3 + 0];
        ty[k] = tar[t * 3 + 1];
        tz[k] = tar[t * 3 + 2];
        best[k] = 1e30f;
    }
#pragma unroll 4
    for (int j = 0; j < CHUNK; ++j) {
        float4 s = sp[j];
#pragma unroll
        for (int k = 0; k < TPT; ++k) {
            float d = fmaf(tx[k], s.x, fmaf(ty[k], s.y, fmaf(tz[k], s.z, s.w)));
            best[k] = fminf(best[k], d);
        }
    }
#pragma unroll
    for (int k = 0; k < TPT; ++k)
        ws[sc * NPTS + t0 + k * 256] = best[k];
}

__global__ __launch_bounds__(256) void nn_sum(const float* __restrict__ tar,
                                              const float* __restrict__ ws,
                                              float* __restrict__ out) {
    const int t = blockIdx.x * 256 + threadIdx.x;
    float m = 1e30f;
#pragma unroll 8
    for (int s2 = 0; s2 < NSPLIT; ++s2)
        m = fminf(m, ws[s2 * NPTS + t]);
    const float x = tar[t * 3 + 0], y = tar[t * 3 + 1], z = tar[t * 3 + 2];
    float v = 0.5f * (m + x * x + y * y + z * z);
    for (int off = 32; off > 0; off >>= 1) v += __shfl_down(v, off, 64);
    __shared__ float wsum[4];
    if ((threadIdx.x & 63) == 0) wsum[threadIdx.x >> 6] = v;
    __syncthreads();
    if (threadIdx.x == 0) atomicAdd(out, wsum[0] + wsum[1] + wsum[2] + wsum[3]);
}

extern "C" void kernel_launch(void* const* d_in, const int* in_sizes, int n_in,
                              void* d_out, int out_size, void* d_ws, size_t ws_size,
                              hipStream_t stream) {
    const float* src = (const float*)d_in[0];
    const float* tar = (const float*)d_in[1];
    float* out = (float*)d_out;
    float* ws  = (float*)d_ws;

    const size_t need = (size_t)NSPLIT * NPTS * sizeof(float);   // 4 MB
    if (ws_size >= need) {
        void* args[] = {(void*)&src, (void*)&tar, (void*)&ws, (void*)&out};
        hipError_t err = hipLaunchCooperativeKernel((const void*)nn_fused,
                                                    dim3(NBLK), dim3(256),
                                                    args, 0, stream);
        if (err != hipSuccess) {
            // Fallback: classic 3-enqueue path (deterministic: same branch every call)
            hipMemsetAsync(d_out, 0, sizeof(float) * (size_t)out_size, stream);
            nn_min<<<dim3(TBLK, NSPLIT), 256, 0, stream>>>(src, tar, ws);
            nn_sum<<<NPTS / 256, 256, 0, stream>>>(tar, ws, out);
        }
    } else {
        // ws unusably small (not expected): do everything with atomic accumulation
        hipMemsetAsync(d_out, 0, sizeof(float) * (size_t)out_size, stream);
        nn_min<<<dim3(TBLK, 1), 256, 0, stream>>>(src, tar, ws); // degenerate, unreachable in practice
        nn_sum<<<NPTS / 256, 256, 0, stream>>>(tar, ws, out);
    }
}

// Round 6
// 89.226 us; speedup vs baseline: 1.7199x; 1.7199x over previous
//
#include <hip/hip_runtime.h>

#define NPTS 16384
#define THREADS 512
#define TPT 4                          // targets per thread
#define TGT_PER_BLK (THREADS * TPT)    // 2048
#define TBLK (NPTS / TGT_PER_BLK)      // 8
#define NSPLIT 64
#define CHUNK (NPTS / NSPLIT)          // 256 sources per chunk
// grid = (8, 64) = 512 blocks x 8 waves = 16 waves/CU (2 blocks/CU)

// Kernel 1: partial min of d2 = ||s||^2 - 2 t.s over one source chunk.
// Inner loop is the empirically-best R2 form: j++, unroll 4, plain fminf
// (grouped j+=4/min3 regressed in R4 — bulk lgkmcnt wait). 512-thread blocks
// double resident waves vs R2 (8 -> 16 waves/CU) to lift VALUBusy from 62%.
__global__ __launch_bounds__(THREADS) void nn_min(const float* __restrict__ src,
                                                  const float* __restrict__ tar,
                                                  float* __restrict__ ws) {
    __shared__ float4 sp[CHUNK];
    const int tid = threadIdx.x;
    const int tb  = blockIdx.x;
    const int sc  = blockIdx.y;
    const int sbase = sc * CHUNK;

    if (tid < CHUNK) {
        float x = src[(sbase + tid) * 3 + 0];
        float y = src[(sbase + tid) * 3 + 1];
        float z = src[(sbase + tid) * 3 + 2];
        sp[tid] = make_float4(-2.0f * x, -2.0f * y, -2.0f * z, x * x + y * y + z * z);
    }
    __syncthreads();

    const int t0 = tb * TGT_PER_BLK + tid;
    float tx[TPT], ty[TPT], tz[TPT], best[TPT];
#pragma unroll
    for (int k = 0; k < TPT; ++k) {
        const int t = t0 + k * THREADS;
        tx[k] = tar[t * 3 + 0];
        ty[k] = tar[t * 3 + 1];
        tz[k] = tar[t * 3 + 2];
        best[k] = 1e30f;
    }

#pragma unroll 4
    for (int j = 0; j < CHUNK; ++j) {
        float4 s = sp[j];
#pragma unroll
        for (int k = 0; k < TPT; ++k) {
            float d = fmaf(tx[k], s.x, fmaf(ty[k], s.y, fmaf(tz[k], s.z, s.w)));
            best[k] = fminf(best[k], d);
        }
    }
#pragma unroll
    for (int k = 0; k < TPT; ++k)
        ws[sc * NPTS + t0 + k * THREADS] = best[k];
}

// Kernel 2: reduce NSPLIT partial mins per target, add ||t||^2, sum 0.5*d2.
__global__ __launch_bounds__(256) void nn_sum(const float* __restrict__ tar,
                                              const float* __restrict__ ws,
                                              float* __restrict__ out) {
    const int t = blockIdx.x * 256 + threadIdx.x;
    float m = 1e30f;
#pragma unroll 8
    for (int sc = 0; sc < NSPLIT; ++sc)
        m = fminf(m, ws[sc * NPTS + t]);
    const float x = tar[t * 3 + 0], y = tar[t * 3 + 1], z = tar[t * 3 + 2];
    float v = 0.5f * (m + x * x + y * y + z * z);

    for (int off = 32; off > 0; off >>= 1) v += __shfl_down(v, off, 64);
    __shared__ float wsum[4];
    if ((threadIdx.x & 63) == 0) wsum[threadIdx.x >> 6] = v;
    __syncthreads();
    if (threadIdx.x == 0) atomicAdd(out, wsum[0] + wsum[1] + wsum[2] + wsum[3]);
}

// Fallback if d_ws is too small (not expected): single kernel, full sweep.
__global__ __launch_bounds__(256) void nn_all(const float* __restrict__ src,
                                              const float* __restrict__ tar,
                                              float* __restrict__ out) {
    __shared__ float4 sp[2048];
    const int tid = threadIdx.x;
    const int t = blockIdx.x * 256 + tid;
    const float tx = tar[t * 3 + 0], ty = tar[t * 3 + 1], tz = tar[t * 3 + 2];
    float best = 1e30f;
    for (int base = 0; base < NPTS; base += 2048) {
        __syncthreads();
        for (int i = tid; i < 2048; i += 256) {
            float x = src[(base + i) * 3 + 0];
            float y = src[(base + i) * 3 + 1];
            float z = src[(base + i) * 3 + 2];
            sp[i] = make_float4(-2.0f * x, -2.0f * y, -2.0f * z, x * x + y * y + z * z);
        }
        __syncthreads();
#pragma unroll 4
        for (int j = 0; j < 2048; ++j) {
            float4 s = sp[j];
            float d = fmaf(tx, s.x, fmaf(ty, s.y, fmaf(tz, s.z, s.w)));
            best = fminf(best, d);
        }
    }
    float v = 0.5f * (best + tx * tx + ty * ty + tz * tz);
    for (int off = 32; off > 0; off >>= 1) v += __shfl_down(v, off, 64);
    __shared__ float wsum[4];
    if ((threadIdx.x & 63) == 0) wsum[threadIdx.x >> 6] = v;
    __syncthreads();
    if (threadIdx.x == 0) atomicAdd(out, wsum[0] + wsum[1] + wsum[2] + wsum[3]);
}

extern "C" void kernel_launch(void* const* d_in, const int* in_sizes, int n_in,
                              void* d_out, int out_size, void* d_ws, size_t ws_size,
                              hipStream_t stream) {
    const float* src = (const float*)d_in[0];
    const float* tar = (const float*)d_in[1];
    float* out = (float*)d_out;
    float* ws  = (float*)d_ws;

    hipMemsetAsync(d_out, 0, sizeof(float) * (size_t)out_size, stream);

    const size_t need = (size_t)NSPLIT * NPTS * sizeof(float);   // 4 MB
    if (ws_size >= need) {
        nn_min<<<dim3(TBLK, NSPLIT), THREADS, 0, stream>>>(src, tar, ws);
        nn_sum<<<NPTS / 256, 256, 0, stream>>>(tar, ws, out);
    } else {
        nn_all<<<NPTS / 256, 256, 0, stream>>>(src, tar, out);
    }
}